// Round 6
// baseline (144.242 us; speedup 1.0000x reference)
//
#include <hip/hip_runtime.h>

// SVF linear time-varying 2-state recurrence as an associative scan over
// affine maps (A,b): s_t = A_t s_{t-1} + b_t, A_t = 2H_t - I.
//
// Single fused kernel, 64 rows x 16 chunks = 1024 blocks, 4/CU co-resident
// (__launch_bounds__(256,4) -> <=128 VGPR). Each block: local scan ->
// publish chunk aggregate -> wait for <=15 same-row predecessors -> emit.
//
// Sync design (the R3 lesson): R3 polled with ACQUIRE agent loads; every
// acquire emits buffer_inv (L1+L2 invalidate) -> ~960 blocks x 1000s of
// polls = invalidate storm, 75us at 4% VALUBusy. Here: RELAXED polls
// (LLC-served, no cache maintenance) + s_sleep backoff + ONE acquire fence
// per block after all waits, issued only after inputs/mix are already in
// registers. Publisher: relaxed agent write-through stores + one release
// flag store (cheap). Deps point only to lower blockIdx; all 1024 blocks
// are co-resident -> no deadlock.

#define BATCH     64
#define SEQ       32768
#define CHUNKS    16
#define CHUNK_LEN (SEQ / CHUNKS)    // 2048
#define TPB       256
#define NWAVE     (TPB / 64)        // 4
#define STEPS     (CHUNK_LEN / TPB) // 8
#define NBLK      (BATCH * CHUNKS)  // 1024

struct Aff { float a00, a01, a10, a11, b0, b1; };

__device__ __forceinline__ Aff aff_ident() {
    Aff r; r.a00 = 1.f; r.a01 = 0.f; r.a10 = 0.f; r.a11 = 1.f; r.b0 = 0.f; r.b1 = 0.f;
    return r;
}

// Apply 'e' (earlier) first, then 'l' (later).
__device__ __forceinline__ Aff compose(const Aff l, const Aff e) {
    Aff r;
    r.a00 = fmaf(l.a00, e.a00, l.a01 * e.a10);
    r.a01 = fmaf(l.a00, e.a01, l.a01 * e.a11);
    r.a10 = fmaf(l.a10, e.a00, l.a11 * e.a10);
    r.a11 = fmaf(l.a10, e.a01, l.a11 * e.a11);
    r.b0  = fmaf(l.a00, e.b0, fmaf(l.a01, e.b1, l.b0));
    r.b1  = fmaf(l.a10, e.b0, fmaf(l.a11, e.b1, l.b1));
    return r;
}

__device__ __forceinline__ Aff step_affine(float gi, float Ri, float xi) {
    float T  = 1.0f / fmaf(gi, gi + Ri, 1.0f);   // 1/(1+g*(g+2R))
    float Tg = T * gi;
    Aff r;
    r.a00 = 2.0f * T - 1.0f;
    r.a01 = -2.0f * Tg;
    r.a10 = 2.0f * Tg;
    r.a11 = 2.0f * fmaf(Tg, Ri, T) - 1.0f;       // 2*T*(2R*g+1)-1
    r.b0  = 2.0f * Tg * xi;
    r.b1  = gi * r.b0;
    return r;
}

__device__ __forceinline__ Aff shfl_up_aff(const Aff v, int d) {
    Aff r;
    r.a00 = __shfl_up(v.a00, d); r.a01 = __shfl_up(v.a01, d);
    r.a10 = __shfl_up(v.a10, d); r.a11 = __shfl_up(v.a11, d);
    r.b0  = __shfl_up(v.b0,  d); r.b1  = __shfl_up(v.b1,  d);
    return r;
}

// Inclusive wave scan (64 lanes, time order = lane order). No barriers.
__device__ __forceinline__ Aff wave_scan_incl(Aff v, int lane) {
#pragma unroll
    for (int off = 1; off < 64; off <<= 1) {
        Aff p = shfl_up_aff(v, off);
        if (lane >= off) v = compose(v, p);
    }
    return v;
}

__device__ __forceinline__ void load8(const float* __restrict__ p, int base, float v[8]) {
    float4 a = *reinterpret_cast<const float4*>(p + base);
    float4 b = *reinterpret_cast<const float4*>(p + base + 4);
    v[0]=a.x; v[1]=a.y; v[2]=a.z; v[3]=a.w; v[4]=b.x; v[5]=b.y; v[6]=b.z; v[7]=b.w;
}

__global__ __launch_bounds__(TPB, 4) void svf_fused2(
    const float* __restrict__ audio, const float* __restrict__ g,
    const float* __restrict__ twoR, const float* __restrict__ mix,
    float* __restrict__ agg, int* __restrict__ flags,
    float* __restrict__ out)
{
    __shared__ Aff wtot[NWAVE];
    __shared__ float csb[2];
    const int blk  = blockIdx.x;
    const int c    = blk & (CHUNKS - 1);       // chunk index within row
    const int t    = threadIdx.x;
    const int lane = t & 63, wave = t >> 6;
    const int base = blk * CHUNK_LEN + t * STEPS;

    // All global inputs into registers BEFORE any cache-maintenance op.
    float gv[STEPS], rv[STEPS], xv[STEPS];
    load8(g, base, gv); load8(twoR, base, rv); load8(audio, base, xv);

    const float4* m4 = reinterpret_cast<const float4*>(mix + 3 * base);
    float mv[24];
#pragma unroll
    for (int q = 0; q < 6; ++q) {
        float4 m = m4[q];
        mv[4*q+0]=m.x; mv[4*q+1]=m.y; mv[4*q+2]=m.z; mv[4*q+3]=m.w;
    }

    // Local 8-step composition + wave scan.
    Aff acc = step_affine(gv[0], rv[0], xv[0]);
#pragma unroll
    for (int i = 1; i < STEPS; ++i)
        acc = compose(step_affine(gv[i], rv[i], xv[i]), acc);
    Aff W = wave_scan_incl(acc, lane);
    if (lane == 63) wtot[wave] = W;
    __syncthreads();

    // Publish chunk aggregate (last chunk of a row is never read).
    if (t == TPB - 1 && c != CHUNKS - 1) {
        Aff A = wtot[0];
#pragma unroll
        for (int w = 1; w < NWAVE; ++w) A = compose(wtot[w], A);
        float* dst = agg + 6 * blk;
        const float* s = (const float*)&A;
#pragma unroll
        for (int k = 0; k < 6; ++k)   // relaxed agent stores: write-through, no L2 dirty lines
            __hip_atomic_store(dst + k, s[k], __ATOMIC_RELAXED, __HIP_MEMORY_SCOPE_AGENT);
        __hip_atomic_store(&flags[blk], 1, __ATOMIC_RELEASE, __HIP_MEMORY_SCOPE_AGENT);
    }

    // Wave 0: wait for predecessors with RELAXED polls (no invalidates),
    // one acquire fence, then gather + scan the <=15 aggregates.
    if (wave == 0) {
        const int pb = blk - c + lane;         // row's chunk 'lane'
        if (lane < c) {
            while (__hip_atomic_load(&flags[pb], __ATOMIC_RELAXED,
                                     __HIP_MEMORY_SCOPE_AGENT) == 0)
                __builtin_amdgcn_s_sleep(16);
        }
        __builtin_amdgcn_fence(__ATOMIC_ACQUIRE, "agent");  // one invalidate/block
        Aff p = aff_ident();
        if (lane < c) {
            const float* s = agg + 6 * pb;
#pragma unroll
            for (int k = 0; k < 6; ++k)
                ((float*)&p)[k] = __hip_atomic_load(s + k, __ATOMIC_RELAXED,
                                                    __HIP_MEMORY_SCOPE_AGENT);
        }
        p = wave_scan_incl(p, lane);
        const int src = (c > 0) ? (c - 1) : 0;
        if (lane == src) {                      // cs = P*[1,1] + b
            csb[0] = p.a00 + p.a01 + p.b0;
            csb[1] = p.a10 + p.a11 + p.b1;
        }
    }
    __syncthreads();

    const float cs0 = csb[0], cs1 = csb[1];

    // Wave prefix P = wtot[wave-1] o ... o wtot[0] (identity for wave 0).
    Aff P = aff_ident();
    for (int wj = 0; wj < wave; ++wj) P = compose(wtot[wj], P);

    // Exclusive block prefix for this thread.
    Aff Wp = shfl_up_aff(W, 1);
    Aff E = (lane == 0) ? P : compose(Wp, P);

    float s0 = fmaf(E.a00, cs0, fmaf(E.a01, cs1, E.b0));
    float s1 = fmaf(E.a10, cs0, fmaf(E.a11, cs1, E.b1));

    float ov[STEPS];
#pragma unroll
    for (int i = 0; i < STEPS; ++i) {
        float gi = gv[i], Ri = rv[i], xi = xv[i];
        float T  = 1.0f / fmaf(gi, gi + Ri, 1.0f);
        float w  = fmaf(gi, xi, s0);                         // g*x + s0
        float Y0 = T * fmaf(-gi, s1, w);                     // bp
        float Y1 = T * fmaf(gi, w, fmaf(Ri, gi, 1.0f) * s1); // lp
        float hp = xi - Ri * Y0 - Y1;
        ov[i] = fmaf(Ri * mv[3*i], Y0, fmaf(mv[3*i+1], Y1, mv[3*i+2] * hp));
        s0 = fmaf(2.0f, Y0, -s0);
        s1 = fmaf(2.0f, Y1, -s1);
    }

    *reinterpret_cast<float4*>(out + base)     = make_float4(ov[0], ov[1], ov[2], ov[3]);
    *reinterpret_cast<float4*>(out + base + 4) = make_float4(ov[4], ov[5], ov[6], ov[7]);
}

extern "C" void kernel_launch(void* const* d_in, const int* in_sizes, int n_in,
                              void* d_out, int out_size, void* d_ws, size_t ws_size,
                              hipStream_t stream) {
    const float* audio = (const float*)d_in[0];
    const float* g     = (const float*)d_in[1];
    const float* twoR  = (const float*)d_in[2];
    const float* mix   = (const float*)d_in[3];
    float* out = (float*)d_out;

    float* agg   = (float*)d_ws;                           // 1024 * 6 floats
    int*   flags = (int*)((char*)d_ws + NBLK * sizeof(Aff));

    hipMemsetAsync(flags, 0, NBLK * sizeof(int), stream);  // ws is 0xAA-poisoned
    svf_fused2<<<NBLK, TPB, 0, stream>>>(audio, g, twoR, mix, agg, flags, out);
}